// Round 11
// baseline (223.208 us; speedup 1.0000x reference)
//
#include <hip/hip_runtime.h>
#include <hip/hip_fp16.h>
#include <stdint.h>
#include <stddef.h>

#define NLVL 16
#define TABROWS 16384
#define BLK 1024
#define NPG 4                         // consecutive points per thread per group
#define NSUB 16                       // sub-range blocks per level
#define PPB (1048576 / NSUB)          // 65536 points per block
#define NITER (PPB / (BLK * NPG))     // 16 gather4 groups per thread
#define GGRID (NLVL * NSUB)           // 256 blocks == 1 per CU (persistent-ish)
#define NPTS 1048576
#define TSCALE 8192.0f                // 2^13: keeps |emb|*scale in fp16-normal range
#define TINV   (1.0f / 8192.0f)
#define MIDOFF (1u << 21)             // intermediate at d_ws + 2 MiB (tables: 1 MiB)

constexpr int RES_[NLVL]  = {16,20,25,32,40,50,64,80,101,128,161,203,256,322,406,512};
// staged bytes per level (4 B/entry fp16x2), rounded up to 16
constexpr int NBYTES_[NLVL] = {16384,32000,62512,65536,65536,65536,65536,65536,
                               65536,65536,65536,65536,65536,65536,65536,65536};

typedef __attribute__((address_space(1))) void gv_t;
typedef __attribute__((address_space(3))) void lv_t;

// ---- kernel 1: convert fp32 tables -> scaled fp16x2 in workspace (1 MiB) ----
__global__ __launch_bounds__(256) void cvt_tab(const float* __restrict__ src,
                                               uint32_t* __restrict__ dst) {
    int i = blockIdx.x * 256 + threadIdx.x;          // 131072 threads, 4 floats each
    float4 v = ((const float4*)src)[i];
    __half2 a = __floats2half2_rn(v.x * TSCALE, v.y * TSCALE);
    __half2 b = __floats2half2_rn(v.z * TSCALE, v.w * TSCALE);
    uint2 o;
    o.x = *(uint32_t*)&a;
    o.y = *(uint32_t*)&b;
    ((uint2*)dst)[i] = o;
}

// one level, one point: trilinear 8-corner gather-blend from LDS table
template<bool HASH>
__device__ __forceinline__ void level_point(const uint32_t* __restrict__ buf,
                                            float px, float py, float pz,
                                            int r, float rh,
                                            float& a0, float& a1) {
    uint32_t t[3][2];
    float w[3][2];
    const float pcp[3] = {px, py, pz};
    const uint32_t PRIME[3]  = {1u, 2654435761u, 805459861u};
    const uint32_t STRIDE[3] = {1u, (uint32_t)r, (uint32_t)(r * r)};
#pragma unroll
    for (int d = 0; d < 3; ++d) {
        // ((x+1)*res)*0.5 - 0.5 == (x+1)*(res*0.5) - 0.5 (pow2 scaling exact)
        float xs = (pcp[d] + 1.0f) * rh - 0.5f;
        float fl = floorf(xs);
        float xf = xs - fl;
        int xi = (int)fl;
        bool v0 = (xi >= 0) && (xi < r);
        bool v1 = (xi >= -1) && (xi < r - 1);
        w[d][0] = v0 ? (1.0f - xf) : 0.0f;           // validity folded into weights
        w[d][1] = v1 ? xf : 0.0f;
        if (HASH) {
            t[d][0] = (uint32_t)xi * PRIME[d];       // uint32 wrap == ref semantics
            t[d][1] = t[d][0] + PRIME[d];            // (xi+1)*P mod 2^32
        } else {
            // zeroed invalid contributions keep idx in [0, r^3) with no mod
            t[d][0] = v0 ? (uint32_t)xi * STRIDE[d] : 0u;
            t[d][1] = v1 ? (uint32_t)(xi + 1) * STRIDE[d] : 0u;
        }
    }
    a0 = 0.0f; a1 = 0.0f;
#pragma unroll
    for (int o0 = 0; o0 < 2; ++o0) {
#pragma unroll
        for (int o1 = 0; o1 < 2; ++o1) {
            uint32_t q01 = HASH ? (t[0][o0] ^ t[1][o1]) : (t[0][o0] + t[1][o1]);
            float w01 = w[0][o0] * w[1][o1];
#pragma unroll
            for (int o2 = 0; o2 < 2; ++o2) {
                uint32_t idx = HASH ? ((q01 ^ t[2][o2]) & 16383u)
                                    : (q01 + t[2][o2]);
                float wc = w01 * w[2][o2];
                uint32_t pk = buf[idx];              // ds_read_b32: fp16x2 entry
                __half2 h = *(__half2*)&pk;
                a0 = fmaf(wc, __low2float(h), a0);
                a1 = fmaf(wc, __high2float(h), a1);
            }
        }
    }
}

// 4 consecutive points: 3 aligned float4 x-loads, 1 uint4 mid-store
template<bool HASH>
__device__ __forceinline__ void gather4(const uint32_t* __restrict__ buf,
                                        const float* __restrict__ x,
                                        uint32_t* __restrict__ dst,
                                        int q, int r, float rh) {
    const float4* xv = (const float4*)(x + 3 * (size_t)q);   // 48 B, 16-B aligned
    float4 v0 = xv[0], v1 = xv[1], v2 = xv[2];
    float px[4] = {v0.x, v0.w, v1.z, v2.y};
    float py[4] = {v0.y, v1.x, v1.w, v2.z};
    float pz[4] = {v0.z, v1.y, v2.x, v2.w};
    uint4 res;
    uint32_t* rp = (uint32_t*)&res;
#pragma unroll
    for (int k = 0; k < NPG; ++k) {
        float a0, a1;
        level_point<HASH>(buf, px[k], py[k], pz[k], r, rh, a0, a1);
        __half2 h = __floats2half2_rn(a0, a1);       // stay in scaled domain
        rp[k] = *(uint32_t*)&h;
    }
    *(uint4*)(dst + q) = res;                        // 16 B coalesced store
}

// ---- kernel 2 (PERSISTENT LEVEL-MAJOR): 256 blocks = 16 levels x 16 subranges
//      = exactly 1 block/CU. Each block stages its level's 64 KiB table ONCE
//      (the only stage + barrier it ever pays), then streams 65536 points
//      through an uninterrupted gather loop. vs round 10: per-CU staging drops
//      8x64KiB -> 1x64KiB and block launch/teardown churn disappears -- the
//      ~16 us/CU of exposed stage-drain (1 block/CU means nothing covers it)
//      is paid once (~2 us) instead of 8 times. Work per block is identical
//      across blocks (balanced tail). Output: scaled fp16x2 level-major mid
//      (64 MiB) in the already-poisoned workspace. VGPR <= 64, no spill. ----
__global__ __launch_bounds__(BLK) void gather(const float* __restrict__ x,
                                              const uint32_t* __restrict__ tab,
                                              uint32_t* __restrict__ mid) {
    __shared__ uint32_t lds[TABROWS];                // 64 KiB, this block's level
    const int tid = threadIdx.x;
    const int lvl = blockIdx.x >> 4;                 // 16 blocks per level
    const int sub = blockIdx.x & (NSUB - 1);

    // stage this level's fp16x2 table slice (<= 64 KiB), once per block
    {
        const int nb = NBYTES_[lvl];
        const char* g = (const char*)tab + (size_t)lvl * TABROWS * 4;
        char* l = (char*)lds;
#pragma unroll
        for (int base = 0; base < TABROWS * 4; base += BLK * 16) {
            int o = base + tid * 16;
            if (o < nb)
                __builtin_amdgcn_global_load_lds((gv_t*)(g + o), (lv_t*)(l + o), 16, 0, 0);
        }
    }
    // single barrier: drains this wave's global_load_lds, then all staged.
    __syncthreads();

    const int r = RES_[lvl];                         // wave-uniform scalar
    const float rh = 0.5f * (float)r;                // exact (pow2 * small int)
    uint32_t* dst = mid + (size_t)lvl * NPTS;
    const int base = sub * PPB + tid * NPG;

    if (lvl >= 3) {                                  // uniform branch: hash path
        for (int g = 0; g < NITER; ++g)
            gather4<true>(lds, x, dst, base + g * (BLK * NPG), r, rh);
    } else {                                         // dense ravel path (lvl 0..2)
        for (int g = 0; g < NITER; ++g)
            gather4<false>(lds, x, dst, base + g * (BLK * NPG), r, rh);
    }
}

// ---- kernel 3: transpose level-major (16, 1M) fp16x2 -> point-major
//      (1M, 16, 2) fp32 with the 2^-13 unscale. Reads: consecutive lanes hit
//      consecutive points -> 256 B/wave/level, 64 MiB total (mostly L3-hot,
//      just written by gather). Writes: 128 B contiguous per thread. ----
__global__ __launch_bounds__(256) void xpose(const uint32_t* __restrict__ mid,
                                             float* __restrict__ out) {
    const int p = blockIdx.x * 256 + threadIdx.x;
    uint32_t v[NLVL];
#pragma unroll
    for (int l = 0; l < NLVL; ++l)
        v[l] = mid[(size_t)l * NPTS + p];            // 16 independent loads in flight
    float4* o4 = (float4*)(out + (size_t)p * (2 * NLVL));
#pragma unroll
    for (int k = 0; k < NLVL / 2; ++k) {
        __half2 h0 = *(__half2*)&v[2*k + 0];
        __half2 h1 = *(__half2*)&v[2*k + 1];
        o4[k] = make_float4(__low2float(h0) * TINV, __high2float(h0) * TINV,
                            __low2float(h1) * TINV, __high2float(h1) * TINV);
    }
}

extern "C" void kernel_launch(void* const* d_in, const int* in_sizes, int n_in,
                              void* d_out, int out_size, void* d_ws, size_t ws_size,
                              hipStream_t stream) {
    const float* x   = (const float*)d_in[0];   // (B, 3) fp32
    const float* emb = (const float*)d_in[1];   // (16, 16384, 2) fp32
    float* out = (float*)d_out;                 // (B, 16, 2) fp32
    uint32_t* tab = (uint32_t*)d_ws;            // fp16x2 tables: 1 MiB at offset 0
    uint32_t* mid = (uint32_t*)((char*)d_ws + MIDOFF); // (16, 1M) fp16x2: 64 MiB

    cvt_tab<<<512, 256, 0, stream>>>(emb, tab);
    gather<<<GGRID, BLK, 0, stream>>>(x, tab, mid);
    xpose<<<NPTS / 256, 256, 0, stream>>>(mid, out);
}